// Round 7
// baseline (379.964 us; speedup 1.0000x reference)
//
#include <hip/hip_runtime.h>

#define HID 20
#define BLK 256

typedef float v2f __attribute__((ext_vector_type(2)));
typedef float v4f __attribute__((ext_vector_type(4)));

// Packed SiLU on two activations: pk_mul, 2x v_exp_f32, pk_add, 2x v_rcp_f32,
// pk_mul. Saturates correctly at both ends (e=inf -> 0; e=0 -> a).
__device__ __forceinline__ v2f silu2(v2f a) {
    v2f m = a * (-1.442695040888963f);
    float e0 = __builtin_amdgcn_exp2f(m.x);
    float e1 = __builtin_amdgcn_exp2f(m.y);
    v2f d = {1.0f + e0, 1.0f + e1};
    v2f r = {__builtin_amdgcn_rcpf(d.x), __builtin_amdgcn_rcpf(d.y)};
    return a * r;
}

// 20->20 layer on FOUR points (two v2f pairs, point-packed like R4 = the best
// structure so far). Each weight w is loaded once (wave-uniform s_load burst)
// and its {w,w} broadcast + any stall is amortized over TWO pk_fma chains.
// The A/B chains are interleaved in source order: ready-made 2x ILP for the
// scheduler on top of the 20-row independence.
__device__ __forceinline__ void layer20_x4(const float* __restrict__ W,
                                           const float* __restrict__ b,
                                           const v2f (&hA)[HID], const v2f (&hB)[HID],
                                           v2f (&oA)[HID], v2f (&oB)[HID]) {
    #pragma unroll
    for (int j = 0; j < HID; ++j) {
        float bj = b[j];
        v2f accA = {bj, bj};
        v2f accB = {bj, bj};
        #pragma unroll
        for (int i = 0; i < HID; ++i) {
            float w = W[j * HID + i];
            v2f ww = {w, w};
            accA = __builtin_elementwise_fma(hA[i], ww, accA);
            accB = __builtin_elementwise_fma(hB[i], ww, accB);
        }
        oA[j] = silu2(accA);
        oB[j] = silu2(accB);
    }
}

// Live set ~100 VGPRs (hA+hB = 80, 2 acc pairs, temps). (256,4) -> 128-VGPR
// cap. Grid is 4 waves/SIMD; 4 independent depth-20 chains/wave hide latency.
__global__ __launch_bounds__(BLK, 4) void SpringEquationNN_70102456205450_kernel(
    const float* __restrict__ t,
    const float* __restrict__ W0, const float* __restrict__ b0,
    const float* __restrict__ W1, const float* __restrict__ b1,
    const float* __restrict__ W2, const float* __restrict__ b2,
    const float* __restrict__ W3, const float* __restrict__ b3,
    const float* __restrict__ W4, const float* __restrict__ b4,
    const float* __restrict__ W5, const float* __restrict__ b5,
    const float* __restrict__ W6, const float* __restrict__ b6,
    const float* __restrict__ W7, const float* __restrict__ b7,
    float* __restrict__ out, int n)
{
    int idx = blockIdx.x * blockDim.x + threadIdx.x;   // quad index
    int p0 = 4 * idx;
    if (p0 >= n) return;

    // 16B coalesced load of 4 consecutive points (N = 1048576, divisible by 4).
    v4f x = *(const v4f*)(t + p0);
    v2f xA = {x.x, x.y};    // points 0,1 -- natural low half
    v2f xB = {x.z, x.w};    // points 2,3 -- natural high half

    v2f hA[HID], hB[HID], gA[HID], gB[HID];

    // Layer 0: 1 -> 20 on all four points
    #pragma unroll
    for (int j = 0; j < HID; ++j) {
        float w = W0[j], bb = b0[j];
        v2f ww = {w, w}, bbb = {bb, bb};
        hA[j] = silu2(__builtin_elementwise_fma(xA, ww, bbb));
        hB[j] = silu2(__builtin_elementwise_fma(xB, ww, bbb));
    }

    // Layers 1..6: 20 -> 20, SiLU. Ping-pong h/g.
    layer20_x4(W1, b1, hA, hB, gA, gB);
    layer20_x4(W2, b2, gA, gB, hA, hB);
    layer20_x4(W3, b3, hA, hB, gA, gB);
    layer20_x4(W4, b4, gA, gB, hA, hB);
    layer20_x4(W5, b5, hA, hB, gA, gB);
    layer20_x4(W6, b6, gA, gB, hA, hB);

    // Layer 7: 20 -> 1, no activation
    float b7v = b7[0];
    v2f accA = {b7v, b7v};
    v2f accB = {b7v, b7v};
    #pragma unroll
    for (int i = 0; i < HID; ++i) {
        float w = W7[i];
        v2f ww = {w, w};
        accA = __builtin_elementwise_fma(hA[i], ww, accA);
        accB = __builtin_elementwise_fma(hB[i], ww, accB);
    }

    // 16B coalesced store of 4 results.
    v4f o = {accA.x, accA.y, accB.x, accB.y};
    *(v4f*)(out + p0) = o;
}

extern "C" void kernel_launch(void* const* d_in, const int* in_sizes, int n_in,
                              void* d_out, int out_size, void* d_ws, size_t ws_size,
                              hipStream_t stream) {
    const float* t  = (const float*)d_in[0];
    const float* W0 = (const float*)d_in[1];
    const float* b0 = (const float*)d_in[2];
    const float* W1 = (const float*)d_in[3];
    const float* b1 = (const float*)d_in[4];
    const float* W2 = (const float*)d_in[5];
    const float* b2 = (const float*)d_in[6];
    const float* W3 = (const float*)d_in[7];
    const float* b3 = (const float*)d_in[8];
    const float* W4 = (const float*)d_in[9];
    const float* b4 = (const float*)d_in[10];
    const float* W5 = (const float*)d_in[11];
    const float* b5 = (const float*)d_in[12];
    const float* W6 = (const float*)d_in[13];
    const float* b6 = (const float*)d_in[14];
    const float* W7 = (const float*)d_in[15];
    const float* b7 = (const float*)d_in[16];
    float* out = (float*)d_out;

    int n = in_sizes[0];           // N points
    int quads = (n + 3) / 4;       // 4 points per thread
    int grid = (quads + BLK - 1) / BLK;
    SpringEquationNN_70102456205450_kernel<<<grid, BLK, 0, stream>>>(
        t, W0, b0, W1, b1, W2, b2, W3, b3, W4, b4, W5, b5, W6, b6, W7, b7,
        out, n);
}

// Round 8
// 158.746 us; speedup vs baseline: 2.3935x; 2.3935x over previous
//
#include <hip/hip_runtime.h>

#define HID 20
#define BLK 256

typedef float v2f __attribute__((ext_vector_type(2)));

// Packed SiLU on two activations: pk_mul, 2x v_exp_f32, pk_add, 2x v_rcp_f32,
// pk_mul. Saturates correctly at both ends (e=inf -> 0; e=0 -> a).
__device__ __forceinline__ v2f silu2(v2f a) {
    v2f m = a * (-1.442695040888963f);
    float e0 = __builtin_amdgcn_exp2f(m.x);
    float e1 = __builtin_amdgcn_exp2f(m.y);
    v2f d = {1.0f + e0, 1.0f + e1};
    v2f r = {__builtin_amdgcn_rcpf(d.x), __builtin_amdgcn_rcpf(d.y)};
    return a * r;
}

// 20->20 layer on TWO points, K-packed:
//  - activations live as 10 v2f K-pairs per point (hA, hB)
//  - weight pair {W[j][2i], W[j][2i+1]} = adjacent floats = wave-uniform
//    s_load_dwordx2 -> DIRECT 64-bit SGPR-pair operand of v_pk_fma_f32.
//    Zero broadcast v_movs (R4's ~2.2k cyc/wave tax).
//  - 4 independent acc chains (2 rows x 2 points) of depth 10 -> ILP to
//    cover the 4-cyc FMA latency inside one wave.
// Row pair finish: 2 scalar adds per row per point (halves of a v2f are
// plain consecutive VGPRs; bias comes straight from an SGPR operand).
__device__ __forceinline__ void layer20_x2(const float* __restrict__ W,
                                           const float* __restrict__ b,
                                           const v2f (&hA)[10], const v2f (&hB)[10],
                                           v2f (&oA)[10], v2f (&oB)[10]) {
    #pragma unroll
    for (int jp = 0; jp < 10; ++jp) {
        const float* r0 = W + 40 * jp;     // row 2*jp
        const float* r1 = r0 + 20;         // row 2*jp+1
        v2f w0 = *(const v2f*)(r0);
        v2f w1 = *(const v2f*)(r1);
        v2f a0A = hA[0] * w0;
        v2f a0B = hB[0] * w0;
        v2f a1A = hA[0] * w1;
        v2f a1B = hB[0] * w1;
        #pragma unroll
        for (int ip = 1; ip < 10; ++ip) {
            v2f u0 = *(const v2f*)(r0 + 2 * ip);
            v2f u1 = *(const v2f*)(r1 + 2 * ip);
            a0A = __builtin_elementwise_fma(hA[ip], u0, a0A);
            a0B = __builtin_elementwise_fma(hB[ip], u0, a0B);
            a1A = __builtin_elementwise_fma(hA[ip], u1, a1A);
            a1B = __builtin_elementwise_fma(hB[ip], u1, a1B);
        }
        float b0v = b[2 * jp], b1v = b[2 * jp + 1];
        v2f sA = { a0A.x + a0A.y + b0v, a1A.x + a1A.y + b1v };
        v2f sB = { a0B.x + a0B.y + b0v, a1B.x + a1B.y + b1v };
        oA[jp] = silu2(sA);
        oB[jp] = silu2(sB);
    }
}

// Live set ~105 VGPRs (hA+hB 40 + oA+oB up to 40 + 4 acc pairs + weight
// temps + silu). (256,4) -> 128-VGPR cap: fits (R7's 4-pt variant at ~170
// spilled to scratch, FETCH 2.3MB -> 200MB; this must stay at ~2.3MB).
__global__ __launch_bounds__(BLK, 4) void SpringEquationNN_70102456205450_kernel(
    const float* __restrict__ t,
    const float* __restrict__ W0, const float* __restrict__ b0,
    const float* __restrict__ W1, const float* __restrict__ b1,
    const float* __restrict__ W2, const float* __restrict__ b2,
    const float* __restrict__ W3, const float* __restrict__ b3,
    const float* __restrict__ W4, const float* __restrict__ b4,
    const float* __restrict__ W5, const float* __restrict__ b5,
    const float* __restrict__ W6, const float* __restrict__ b6,
    const float* __restrict__ W7, const float* __restrict__ b7,
    float* __restrict__ out, int n)
{
    int idx = blockIdx.x * blockDim.x + threadIdx.x;   // pair-of-points index
    int p0 = 2 * idx;
    if (p0 >= n) return;

    v2f x = *(const v2f*)(t + p0);   // 8B coalesced: points p0, p0+1

    v2f hA[10], hB[10], gA[10], gB[10];

    // Layer 0: 1 -> 20. Row j needs x*W0[j]+b0[j]; pack rows (2jp, 2jp+1)
    // into one v2f so the weight/bias pair is again a natural SGPR pair.
    #pragma unroll
    for (int jp = 0; jp < 10; ++jp) {
        v2f w  = *(const v2f*)(W0 + 2 * jp);
        v2f bb = *(const v2f*)(b0 + 2 * jp);
        hA[jp] = silu2(__builtin_elementwise_fma((v2f){x.x, x.x}, w, bb));
        hB[jp] = silu2(__builtin_elementwise_fma((v2f){x.y, x.y}, w, bb));
    }

    // Layers 1..6: 20 -> 20, SiLU. Ping-pong h/g.
    layer20_x2(W1, b1, hA, hB, gA, gB);
    layer20_x2(W2, b2, gA, gB, hA, hB);
    layer20_x2(W3, b3, hA, hB, gA, gB);
    layer20_x2(W4, b4, gA, gB, hA, hB);
    layer20_x2(W5, b5, hA, hB, gA, gB);
    layer20_x2(W6, b6, gA, gB, hA, hB);

    // Layer 7: 20 -> 1, no activation. K-packed dot per point.
    v2f w7 = *(const v2f*)(W7);
    v2f aA = hA[0] * w7;
    v2f aB = hB[0] * w7;
    #pragma unroll
    for (int ip = 1; ip < 10; ++ip) {
        v2f w = *(const v2f*)(W7 + 2 * ip);
        aA = __builtin_elementwise_fma(hA[ip], w, aA);
        aB = __builtin_elementwise_fma(hB[ip], w, aB);
    }
    float bb7 = b7[0];
    v2f o = { aA.x + aA.y + bb7, aB.x + aB.y + bb7 };
    *(v2f*)(out + p0) = o;   // 8B coalesced
}

extern "C" void kernel_launch(void* const* d_in, const int* in_sizes, int n_in,
                              void* d_out, int out_size, void* d_ws, size_t ws_size,
                              hipStream_t stream) {
    const float* t  = (const float*)d_in[0];
    const float* W0 = (const float*)d_in[1];
    const float* b0 = (const float*)d_in[2];
    const float* W1 = (const float*)d_in[3];
    const float* b1 = (const float*)d_in[4];
    const float* W2 = (const float*)d_in[5];
    const float* b2 = (const float*)d_in[6];
    const float* W3 = (const float*)d_in[7];
    const float* b3 = (const float*)d_in[8];
    const float* W4 = (const float*)d_in[9];
    const float* b4 = (const float*)d_in[10];
    const float* W5 = (const float*)d_in[11];
    const float* b5 = (const float*)d_in[12];
    const float* W6 = (const float*)d_in[13];
    const float* b6 = (const float*)d_in[14];
    const float* W7 = (const float*)d_in[15];
    const float* b7 = (const float*)d_in[16];
    float* out = (float*)d_out;

    int n = in_sizes[0];           // N points
    int pairs = (n + 1) / 2;       // 2 points per thread
    int grid = (pairs + BLK - 1) / BLK;
    SpringEquationNN_70102456205450_kernel<<<grid, BLK, 0, stream>>>(
        t, W0, b0, W1, b1, W2, b2, W3, b3, W4, b4, W5, b5, W6, b6, W7, b7,
        out, n);
}

// Round 9
// 158.558 us; speedup vs baseline: 2.3964x; 1.0012x over previous
//
#include <hip/hip_runtime.h>

#define HID 20
#define BLK 256

typedef float v2f __attribute__((ext_vector_type(2)));

// Forced VOP3P: one instruction per 2 MACs, weight pair direct from an
// even-aligned SGPR pair (the "s" constraint on a 64-bit double). No
// broadcast v_movs -- the exact form the compiler refused to emit in R4-R8.
#define PK_MUL(acc, w, h) \
    asm("v_pk_mul_f32 %0, %1, %2" : "=v"(acc) : "s"(w), "v"(h))
#define PK_FMA(acc, w, h) \
    asm("v_pk_fma_f32 %0, %1, %2, %0" : "+v"(acc) : "s"(w), "v"(h))

// Packed SiLU on two activations (C level: pk_mul/add + 2x exp + 2x rcp).
__device__ __forceinline__ v2f silu2(v2f a) {
    v2f m = a * (-1.442695040888963f);
    float e0 = __builtin_amdgcn_exp2f(m.x);
    float e1 = __builtin_amdgcn_exp2f(m.y);
    v2f d = {1.0f + e0, 1.0f + e1};
    v2f r = {__builtin_amdgcn_rcpf(d.x), __builtin_amdgcn_rcpf(d.y)};
    return a * r;
}

// 20->20 layer on TWO points, K-packed, asm core.
// Wd = weight matrix viewed as doubles (10 per row, rows 10 doubles apart).
// 4 independent chains (2 rows x 2 points), depth 10 -> ILP covers FMA latency.
__device__ __forceinline__ void layer20_x2(const double* __restrict__ Wd,
                                           const float* __restrict__ b,
                                           const v2f (&hA)[10], const v2f (&hB)[10],
                                           v2f (&oA)[10], v2f (&oB)[10]) {
    #pragma unroll
    for (int jp = 0; jp < 10; ++jp) {
        const double* r0 = Wd + 20 * jp;      // row 2*jp   (10 doubles)
        const double* r1 = r0 + 10;           // row 2*jp+1
        v2f a0A, a0B, a1A, a1B;
        double w0 = r0[0], w1 = r1[0];
        PK_MUL(a0A, w0, hA[0]);
        PK_MUL(a0B, w0, hB[0]);
        PK_MUL(a1A, w1, hA[0]);
        PK_MUL(a1B, w1, hB[0]);
        #pragma unroll
        for (int ip = 1; ip < 10; ++ip) {
            double u0 = r0[ip], u1 = r1[ip];
            PK_FMA(a0A, u0, hA[ip]);
            PK_FMA(a0B, u0, hB[ip]);
            PK_FMA(a1A, u1, hA[ip]);
            PK_FMA(a1B, u1, hB[ip]);
        }
        float b0v = b[2 * jp], b1v = b[2 * jp + 1];
        v2f sA = { a0A.x + a0A.y + b0v, a1A.x + a1A.y + b1v };
        v2f sB = { a0B.x + a0B.y + b0v, a1B.x + a1B.y + b1v };
        oA[jp] = silu2(sA);
        oB[jp] = silu2(sB);
    }
}

// Live set ~100 VGPRs (hA+hB 40, oA+oB filling, 4 accs, silu temps).
// (256,4) -> 128-VGPR cap: fits; R7 proved >128 spills catastrophically.
__global__ __launch_bounds__(BLK, 4) void SpringEquationNN_70102456205450_kernel(
    const float* __restrict__ t,
    const float* __restrict__ W0, const float* __restrict__ b0,
    const float* __restrict__ W1, const float* __restrict__ b1,
    const float* __restrict__ W2, const float* __restrict__ b2,
    const float* __restrict__ W3, const float* __restrict__ b3,
    const float* __restrict__ W4, const float* __restrict__ b4,
    const float* __restrict__ W5, const float* __restrict__ b5,
    const float* __restrict__ W6, const float* __restrict__ b6,
    const float* __restrict__ W7, const float* __restrict__ b7,
    float* __restrict__ out, int n)
{
    int idx = blockIdx.x * blockDim.x + threadIdx.x;   // pair-of-points index
    int p0 = 2 * idx;
    if (p0 >= n) return;

    v2f x = *(const v2f*)(t + p0);   // 8B coalesced: points p0, p0+1

    v2f hA[10], hB[10], gA[10], gB[10];

    // Layer 0: 1 -> 20. Rows (2jp,2jp+1) packed; weight/bias = SGPR pairs.
    #pragma unroll
    for (int jp = 0; jp < 10; ++jp) {
        double wd = ((const double*)W0)[jp];
        v2f w; __builtin_memcpy(&w, &wd, 8);
        v2f bb = *(const v2f*)(b0 + 2 * jp);
        hA[jp] = silu2(__builtin_elementwise_fma((v2f){x.x, x.x}, w, bb));
        hB[jp] = silu2(__builtin_elementwise_fma((v2f){x.y, x.y}, w, bb));
    }

    // Layers 1..6: 20 -> 20, SiLU. Ping-pong h/g.
    layer20_x2((const double*)W1, b1, hA, hB, gA, gB);
    layer20_x2((const double*)W2, b2, gA, gB, hA, hB);
    layer20_x2((const double*)W3, b3, hA, hB, gA, gB);
    layer20_x2((const double*)W4, b4, gA, gB, hA, hB);
    layer20_x2((const double*)W5, b5, hA, hB, gA, gB);
    layer20_x2((const double*)W6, b6, gA, gB, hA, hB);

    // Layer 7: 20 -> 1, no activation. K-packed dot per point, asm core.
    const double* W7d = (const double*)W7;
    v2f aA, aB;
    double w70 = W7d[0];
    PK_MUL(aA, w70, hA[0]);
    PK_MUL(aB, w70, hB[0]);
    #pragma unroll
    for (int ip = 1; ip < 10; ++ip) {
        double w = W7d[ip];
        PK_FMA(aA, w, hA[ip]);
        PK_FMA(aB, w, hB[ip]);
    }
    float bb7 = b7[0];
    v2f o = { aA.x + aA.y + bb7, aB.x + aB.y + bb7 };
    *(v2f*)(out + p0) = o;   // 8B coalesced
}

extern "C" void kernel_launch(void* const* d_in, const int* in_sizes, int n_in,
                              void* d_out, int out_size, void* d_ws, size_t ws_size,
                              hipStream_t stream) {
    const float* t  = (const float*)d_in[0];
    const float* W0 = (const float*)d_in[1];
    const float* b0 = (const float*)d_in[2];
    const float* W1 = (const float*)d_in[3];
    const float* b1 = (const float*)d_in[4];
    const float* W2 = (const float*)d_in[5];
    const float* b2 = (const float*)d_in[6];
    const float* W3 = (const float*)d_in[7];
    const float* b3 = (const float*)d_in[8];
    const float* W4 = (const float*)d_in[9];
    const float* b4 = (const float*)d_in[10];
    const float* W5 = (const float*)d_in[11];
    const float* b5 = (const float*)d_in[12];
    const float* W6 = (const float*)d_in[13];
    const float* b6 = (const float*)d_in[14];
    const float* W7 = (const float*)d_in[15];
    const float* b7 = (const float*)d_in[16];
    float* out = (float*)d_out;

    int n = in_sizes[0];           // N points
    int pairs = (n + 1) / 2;       // 2 points per thread
    int grid = (pairs + BLK - 1) / BLK;
    SpringEquationNN_70102456205450_kernel<<<grid, BLK, 0, stream>>>(
        t, W0, b0, W1, b1, W2, b2, W3, b3, W4, b4, W5, b5, W6, b6, W7, b7,
        out, n);
}